// Round 1
// 282.974 us; speedup vs baseline: 1.0156x; 1.0156x over previous
//
#include <hip/hip_runtime.h>
#include <hip/hip_bf16.h>

#define D 256

typedef __bf16 bf16x8 __attribute__((ext_vector_type(8)));
typedef float  f32x4  __attribute__((ext_vector_type(4)));
typedef unsigned short ushort8v __attribute__((ext_vector_type(8)));

static __device__ __forceinline__ unsigned short f2bf_rne(float f) {
    unsigned u = __float_as_uint(f);
    u += 0x7fff + ((u >> 16) & 1);
    return (unsigned short)(u >> 16);
}
static __device__ __forceinline__ float bf2f(unsigned short h) {
    return __uint_as_float(((unsigned)h) << 16);
}
static __device__ __forceinline__ unsigned short f2h(float f) {
    _Float16 h = (_Float16)f;
    unsigned short u; __builtin_memcpy(&u, &h, 2); return u;
}
static __device__ __forceinline__ float h2f(unsigned short u) {
    _Float16 h; __builtin_memcpy(&h, &u, 2); return (float)h;
}

static __device__ __forceinline__ void cp16(const unsigned short* g, unsigned short* l) {
    __builtin_amdgcn_global_load_lds(
        (const __attribute__((address_space(1))) void*)g,
        (__attribute__((address_space(3))) void*)l, 16, 0, 0);
}

static __device__ __forceinline__ void split8(float4 a, float4 b,
                                              ushort8v& h, ushort8v& l) {
    float v[8] = {a.x, a.y, a.z, a.w, b.x, b.y, b.z, b.w};
    #pragma unroll
    for (int i = 0; i < 8; ++i) {
        unsigned short hh = f2bf_rne(v[i]);
        h[i] = hh;
        l[i] = f2bf_rne(v[i] - bf2f(hh));
    }
}

// Weights-only conversion: blocks [0,256) split W into bf16 hi/lo (transposed
// for Wq/Wk), block 256 computes wstar = Wk^T bq.  Tiny (~3 us) so the big
// feat->fp16 conversion no longer serializes in front of the MT/G gemms.
__global__ __launch_bounds__(256) void convert_w(
    const float* __restrict__ Wq, const float* __restrict__ Wk,
    const float* __restrict__ Wv, const float* __restrict__ bq,
    unsigned short* __restrict__ wqT_h, unsigned short* __restrict__ wqT_l,
    unsigned short* __restrict__ wkT_h, unsigned short* __restrict__ wkT_l,
    unsigned short* __restrict__ wv_h,  unsigned short* __restrict__ wv_l,
    float* __restrict__ wstar)
{
    const int bx = blockIdx.x;
    if (bx == 256) {
        int k = threadIdx.x;
        float s = 0.f;
        for (int n = 0; n < D; ++n) s = fmaf(Wk[n * D + k], bq[n], s);
        wstar[k] = s;
        return;
    }
    int i = bx * 256 + threadIdx.x;
    int r = i >> 8, cc = i & 255;
    int ti = cc * D + r;
    float q = Wq[i]; unsigned short qh = f2bf_rne(q);
    wqT_h[ti] = qh; wqT_l[ti] = f2bf_rne(q - bf2f(qh));
    float k = Wk[i]; unsigned short kh = f2bf_rne(k);
    wkT_h[ti] = kh; wkT_l[ti] = f2bf_rne(k - bf2f(kh));
    float v = Wv[i]; unsigned short vh = f2bf_rne(v);
    wv_h[i] = vh; wv_l[i] = f2bf_rne(v - bf2f(vh));
}

// C[m][n] = sum_k A[row(m)][k]*B[n][k] (+bias[n]).  BM=64 x BN tile, BK=32,
// 16x16x32 bf16 MFMA, 3-product hi/lo split (~f32 accuracy).
// AF32: A is f32 (optionally gathered via idx), split on the fly.
// FUSE: BN must equal ldc (=256, full rows in-block): epilogue applies
//       tanh + row L2-normalize and writes f32 directly.
// CONV: blocks with blockIdx.x >= gx0 instead convert 4 feat rows to fp16
//       (8 rows per x-index across the 2 y-slices) — overlaps the BW-bound
//       table conversion with the compute-bound gemm in one launch.
template <int BN, bool PAIR_OUT, bool AF32, bool FUSE, bool CONV>
__global__ __launch_bounds__(256) void gemm_t(
    const unsigned short* __restrict__ Ah, const unsigned short* __restrict__ Al,
    const float* __restrict__ Af,
    const int* __restrict__ idx, int M,
    const unsigned short* __restrict__ Bh, const unsigned short* __restrict__ Bl,
    const float* __restrict__ bias,
    float* __restrict__ Cf, unsigned short* __restrict__ Ch,
    unsigned short* __restrict__ Cl, int ldc,
    const float* __restrict__ feat, unsigned short* __restrict__ f16tab,
    int T, int gx0)
{
    if constexpr (CONV) {
        if ((int)blockIdx.x >= gx0) {
            const int w = threadIdx.x >> 6, l = threadIdx.x & 63;
            int row = ((int)blockIdx.x - gx0) * 8 + (int)blockIdx.y * 4 + w;
            if (row < T) {
                float4 v = ((const float4*)(feat + (size_t)row * D))[l];
                ushort4 h;
                h.x = f2h(v.x); h.y = f2h(v.y); h.z = f2h(v.z); h.w = f2h(v.w);
                ((ushort4*)(f16tab + (size_t)row * D))[l] = h;
            }
            return;
        }
    }

    constexpr int RW = BN / 4;        // cols (and staged B rows) per wave
    constexpr int JT = RW / 16;       // 16-wide col tiles per wave

    __shared__ __align__(16) unsigned short sAh[64 * 32], sAl[64 * 32];
    __shared__ __align__(16) unsigned short sBh[BN * 32], sBl[BN * 32];
    __shared__ float red[FUSE ? 256 : 4];

    const int t = threadIdx.x;
    const int w = t >> 6, lane = t & 63;
    const int quad = lane >> 4, mcol = lane & 15;
    const int m0 = blockIdx.x * 64, n0 = blockIdx.y * BN;

    const int arow = t >> 2;              // 0..63
    const int kchunk = (t & 3) * 8;

    int ar = m0 + arow; if (ar > M - 1) ar = M - 1;
    if (idx) ar = idx[ar];

    const unsigned short *aph = nullptr, *apl = nullptr;
    const float *apf = nullptr;
    if constexpr (AF32) {
        apf = Af + (size_t)ar * D + kchunk;
    } else {
        aph = Ah + (size_t)ar * D + kchunk;
        apl = Al + (size_t)ar * D + kchunk;
    }

    // B staging pointers: wave w stages rows [w*RW, w*RW+RW)
    const unsigned short* bh[JT];
    const unsigned short* bl[JT];
    #pragma unroll
    for (int p = 0; p < JT; ++p) {
        int row = n0 + w * RW + p * 16 + (lane >> 2);
        bh[p] = Bh + (size_t)row * D + kchunk;
        bl[p] = Bl + (size_t)row * D + kchunk;
    }

    f32x4 acc[4][JT];
    #pragma unroll
    for (int i = 0; i < 4; ++i)
        #pragma unroll
        for (int j = 0; j < JT; ++j) acc[i][j] = (f32x4){0.f, 0.f, 0.f, 0.f};

    #pragma unroll
    for (int kb = 0; kb < D; kb += 32) {
        #pragma unroll
        for (int p = 0; p < JT; ++p) {
            cp16(bh[p] + kb, &sBh[(w * RW + p * 16) * 32]);
            cp16(bl[p] + kb, &sBl[(w * RW + p * 16) * 32]);
        }
        if constexpr (AF32) {
            float4 x0 = *(const float4*)(apf + kb);
            float4 x1 = *(const float4*)(apf + kb + 4);
            ushort8v h, l;
            split8(x0, x1, h, l);
            *(ushort8v*)&sAh[arow * 32 + kchunk] = h;
            *(ushort8v*)&sAl[arow * 32 + kchunk] = l;
        } else {
            cp16(aph + kb, &sAh[w * 512]);
            cp16(apl + kb, &sAl[w * 512]);
        }
        __syncthreads();

        bf16x8 fah[4], fal[4], fbh[JT], fbl[JT];
        #pragma unroll
        for (int i = 0; i < 4; ++i) {
            fah[i] = *(const bf16x8*)&sAh[(i * 16 + mcol) * 32 + quad * 8];
            fal[i] = *(const bf16x8*)&sAl[(i * 16 + mcol) * 32 + quad * 8];
        }
        #pragma unroll
        for (int j = 0; j < JT; ++j) {
            fbh[j] = *(const bf16x8*)&sBh[(w * RW + j * 16 + mcol) * 32 + quad * 8];
            fbl[j] = *(const bf16x8*)&sBl[(w * RW + j * 16 + mcol) * 32 + quad * 8];
        }
        #pragma unroll
        for (int i = 0; i < 4; ++i)
            #pragma unroll
            for (int j = 0; j < JT; ++j) {
                acc[i][j] = __builtin_amdgcn_mfma_f32_16x16x32_bf16(fah[i], fbh[j], acc[i][j], 0, 0, 0);
                acc[i][j] = __builtin_amdgcn_mfma_f32_16x16x32_bf16(fah[i], fbl[j], acc[i][j], 0, 0, 0);
                acc[i][j] = __builtin_amdgcn_mfma_f32_16x16x32_bf16(fal[i], fbh[j], acc[i][j], 0, 0, 0);
            }
        __syncthreads();
    }

    float bb[JT];
    #pragma unroll
    for (int j = 0; j < JT; ++j) bb[j] = bias ? bias[n0 + w * RW + j * 16 + mcol] : 0.f;

    if constexpr (FUSE) {
        // tanh, then row-wise sum of squares
        float ss[4][4];
        #pragma unroll
        for (int i = 0; i < 4; ++i)
            #pragma unroll
            for (int r = 0; r < 4; ++r) {
                float s = 0.f;
                #pragma unroll
                for (int j = 0; j < JT; ++j) {
                    float v = tanhf(acc[i][j][r] + bb[j]);
                    acc[i][j][r] = v;
                    s = fmaf(v, v, s);
                }
                #pragma unroll
                for (int off = 1; off < 16; off <<= 1) s += __shfl_xor(s, off);
                ss[i][r] = s;
            }
        if (mcol == 0) {
            #pragma unroll
            for (int i = 0; i < 4; ++i)
                #pragma unroll
                for (int r = 0; r < 4; ++r)
                    red[(i * 16 + quad * 4 + r) * 4 + w] = ss[i][r];
        }
        __syncthreads();
        #pragma unroll
        for (int i = 0; i < 4; ++i)
            #pragma unroll
            for (int r = 0; r < 4; ++r) {
                int row = i * 16 + quad * 4 + r;
                float tot = red[row * 4] + red[row * 4 + 1] +
                            red[row * 4 + 2] + red[row * 4 + 3];
                float inv = 1.0f / fmaxf(sqrtf(tot), 1e-12f);
                int m = m0 + row;
                if (m < M) {
                    #pragma unroll
                    for (int j = 0; j < JT; ++j)
                        Cf[(size_t)m * ldc + n0 + w * RW + j * 16 + mcol] =
                            acc[i][j][r] * inv;
                }
            }
    } else {
        #pragma unroll
        for (int i = 0; i < 4; ++i) {
            #pragma unroll
            for (int r = 0; r < 4; ++r) {
                int m = m0 + i * 16 + quad * 4 + r;
                if (m < M) {
                    #pragma unroll
                    for (int j = 0; j < JT; ++j) {
                        float v = acc[i][j][r] + bb[j];
                        size_t off = (size_t)m * ldc + n0 + w * RW + j * 16 + mcol;
                        if constexpr (PAIR_OUT) {
                            unsigned short hh = f2bf_rne(v);
                            Ch[off] = hh;
                            Cl[off] = f2bf_rne(v - bf2f(hh));
                        } else {
                            Cf[off] = v;
                        }
                    }
                }
            }
        }
    }
}

// One WAVE per node. Two fp16 rows per load instruction:
// lanes 0-31 row 2p, lanes 32-63 row 2p+1, 16B/lane. Scores reduce over a
// 32-lane half (5 xor steps); lane l owns score 2*(l&31)+(l>>5).
// wstar is pre-folded into G, so score = G'.f_t directly.
template <int S>
__global__ __launch_bounds__(256) void attn_wave2(
    const int* __restrict__ node_ids, const int* __restrict__ neigh_ids,
    const float* __restrict__ G, const unsigned short* __restrict__ f16tab,
    float* __restrict__ mixf, int N)
{
    constexpr int SP1 = S + 1;          // 33
    constexpr int NP  = (SP1 + 1) / 2;  // 17 row-pairs
    const int w = threadIdx.x >> 6, l = threadIdx.x & 63;
    const int n = blockIdx.x * 4 + w;
    if (n >= N) return;

    const int h  = l >> 5;      // half: 0 = even rows, 1 = odd rows
    const int j  = l & 31;      // position within half

    int myid = 0;
    if (l < SP1) myid = (l == 0) ? node_ids[n] : neigh_ids[(size_t)n * S + (l - 1)];

    // G' chunk: dims j*8 .. j*8+7
    float4 g0 = ((const float4*)(G + (size_t)n * D))[j * 2];
    float4 g1 = ((const float4*)(G + (size_t)n * D))[j * 2 + 1];
    float gv[8] = {g0.x, g0.y, g0.z, g0.w, g1.x, g1.y, g1.z, g1.w};

    // load all row-pairs (16B/lane; 512B per row per 32 lanes)
    ushort8v rows[NP];
    #pragma unroll
    for (int p = 0; p < NP; ++p) {
        int rix = 2 * p + h; if (rix > SP1 - 1) rix = SP1 - 1;
        int idk = __shfl(myid, rix);
        rows[p] = ((const ushort8v*)(f16tab + (size_t)idk * D))[j];
    }

    // scores
    float score = -1e30f;
    #pragma unroll
    for (int p = 0; p < NP; ++p) {
        ushort8v r = rows[p];
        float s = 0.f;
        #pragma unroll
        for (int i = 0; i < 8; ++i) s = fmaf(gv[i], h2f(r[i]), s);
        #pragma unroll
        for (int off = 1; off < 32; off <<= 1) s += __shfl_xor(s, off);
        if (j == p) score = s;
    }
    const int myrow = 2 * j + h;
    if (myrow >= SP1) score = -1e30f;

    // softmax across all 64 lanes (permutation-invariant)
    float m = score;
    #pragma unroll
    for (int off = 1; off < 64; off <<= 1) m = fmaxf(m, __shfl_xor(m, off));
    float e = (myrow < SP1) ? __expf(score - m) : 0.f;
    float s = e;
    #pragma unroll
    for (int off = 1; off < 64; off <<= 1) s += __shfl_xor(s, off);
    float attn = e / s;

    // mix: half h accumulates its parity's rows, then combine halves
    float mix[8] = {0.f, 0.f, 0.f, 0.f, 0.f, 0.f, 0.f, 0.f};
    #pragma unroll
    for (int p = 0; p < NP; ++p) {
        float a = __shfl(attn, p + (l & 32));   // lane p (even) / 32+p (odd)
        ushort8v r = rows[p];
        #pragma unroll
        for (int i = 0; i < 8; ++i) mix[i] = fmaf(a, h2f(r[i]), mix[i]);
    }
    #pragma unroll
    for (int i = 0; i < 8; ++i) mix[i] += __shfl_xor(mix[i], 32);

    float4 v = {mix[4 * h + 0], mix[4 * h + 1], mix[4 * h + 2], mix[4 * h + 3]};
    ((float4*)(mixf + (size_t)n * D))[j * 2 + h] = v;
}

// generic fallback (S != 32)
__global__ __launch_bounds__(256) void attn_dyn(
    const int* __restrict__ node_ids, const int* __restrict__ neigh_ids,
    const float* __restrict__ G, const unsigned short* __restrict__ f16tab,
    float* __restrict__ mixf, int S)
{
    const int n = blockIdx.x, t = threadIdx.x;
    const int w = t >> 6, l = t & 63;
    __shared__ int   ids[128];
    __shared__ float sc[128];
    const int SP1 = S + 1;
    for (int k = t; k < SP1; k += 256)
        ids[k] = (k == 0) ? node_ids[n] : neigh_ids[(size_t)n * S + k - 1];
    __syncthreads();
    float4 g = ((const float4*)(G + (size_t)n * D))[l];
    for (int k = w; k < SP1; k += 4) {
        int id = ids[k];
        ushort4 h4 = ((const ushort4*)(f16tab + (size_t)id * D))[l];
        float p = g.x * h2f(h4.x) + g.y * h2f(h4.y) +
                  g.z * h2f(h4.z) + g.w * h2f(h4.w);
        #pragma unroll
        for (int off = 32; off > 0; off >>= 1) p += __shfl_down(p, off);
        if (l == 0) sc[k] = p;
    }
    __syncthreads();
    if (t < 64) {
        float v = (t < SP1) ? sc[t] : -1e30f;
        float m = v;
        #pragma unroll
        for (int off = 32; off > 0; off >>= 1) m = fmaxf(m, __shfl_down(m, off));
        m = __shfl(m, 0);
        float e = (t < SP1) ? __expf(v - m) : 0.f;
        float s = e;
        #pragma unroll
        for (int off = 32; off > 0; off >>= 1) s += __shfl_down(s, off);
        s = __shfl(s, 0);
        if (t < SP1) sc[t] = e / s;
    }
    __syncthreads();
    float mix = 0.f;
    for (int k = 0; k < SP1; ++k)
        mix = fmaf(sc[k], h2f(f16tab[(size_t)ids[k] * D + t]), mix);
    mixf[(size_t)n * D + t] = mix;
}

extern "C" void kernel_launch(void* const* d_in, const int* in_sizes, int n_in,
                              void* d_out, int out_size, void* d_ws, size_t ws_size,
                              hipStream_t stream) {
    const int*   node_ids  = (const int*)  d_in[0];
    const int*   neigh_ids = (const int*)  d_in[1];
    const float* feat      = (const float*)d_in[2];
    const float* Wq        = (const float*)d_in[3];
    const float* bq        = (const float*)d_in[4];
    const float* Wk        = (const float*)d_in[5];
    // bk (d_in[6]) is softmax-invariant — unused
    const float* Wv        = (const float*)d_in[7];
    const float* bv        = (const float*)d_in[8];
    float*       out       = (float*)d_out;

    const int N = in_sizes[0];            // 20000
    const int S = in_sizes[1] / N;        // 32
    const int T = in_sizes[2] / D;        // 100000

    // ---- workspace (~94 MB) ----
    unsigned short* f16tab = (unsigned short*)d_ws;             // T*D fp16
    float*          G      = (float*)(f16tab + (size_t)T * D);  // N*D f32
    float*          mixf   = G + (size_t)N * D;                 // N*D f32
    unsigned short* wqT_h  = (unsigned short*)(mixf + (size_t)N * D); // 6 x D*D
    unsigned short* wqT_l  = wqT_h + D * D;
    unsigned short* wkT_h  = wqT_l + D * D;
    unsigned short* wkT_l  = wkT_h + D * D;
    unsigned short* wv_h   = wkT_l + D * D;
    unsigned short* wv_l   = wv_h + D * D;
    unsigned short* MT_h   = wv_l + D * D;                      // 2 x D*D
    unsigned short* MT_l   = MT_h + D * D;
    float*          wstar  = (float*)(MT_l + D * D);            // D

    // 1) weight conversions + wstar only (~3 us; no longer blocks on the
    //    100k-row feat conversion)
    convert_w<<<257, 256, 0, stream>>>(
        Wq, Wk, Wv, bq,
        wqT_h, wqT_l, wkT_h, wkT_l, wv_h, wv_l, wstar);

    // 2) MT = Wk^T Wq -> bf16 hi/lo pair
    {
        dim3 grid(4, 2);
        gemm_t<128, true, false, false, false><<<grid, 256, 0, stream>>>(
            wkT_h, wkT_l, nullptr, nullptr, D, wqT_h, wqT_l, nullptr,
            nullptr, MT_h, MT_l, D, nullptr, nullptr, 0, 0);
    }
    // 3) G' = feat[node_ids] . MT + wstar  (wstar folded as bias)
    //    + feat->fp16 table conversion merged into the same launch:
    //    BW-bound convert overlaps the compute-bound gemm.
    {
        const int gx0 = (N + 63) / 64;        // gemm x-tiles (313)
        const int cbx = (T + 7) / 8;          // convert x-indices (12500)
        dim3 grid(gx0 + cbx, 2);
        gemm_t<128, false, true, false, true><<<grid, 256, 0, stream>>>(
            nullptr, nullptr, feat, node_ids, N, MT_h, MT_l, wstar,
            G, nullptr, nullptr, D, feat, f16tab, T, gx0);
    }
    // 4) attention -> mixfeat (f32)
    if (S == 32)
        attn_wave2<32><<<(N + 3) / 4, 256, 0, stream>>>(
            node_ids, neigh_ids, G, f16tab, mixf, N);
    else
        attn_dyn<<<N, 256, 0, stream>>>(node_ids, neigh_ids, G, f16tab, mixf, S);

    // 5) out = normalize(tanh(mixfeat @ Wv^T + bv)) — fused epilogue
    {
        dim3 grid((N + 63) / 64, 1);
        gemm_t<256, false, true, true, false><<<grid, 256, 0, stream>>>(
            nullptr, nullptr, mixf, nullptr, N, wv_h, wv_l, bv,
            out, nullptr, nullptr, D, nullptr, nullptr, 0, 0);
    }
}